// Round 2
// baseline (700.872 us; speedup 1.0000x reference)
//
#include <hip/hip_runtime.h>
#include <math.h>

// Problem constants (B, N, D_IN, D_STATE) = (32, 4096, 1024, 1024).
// softmax is shift-invariant, so the hidden@w_h + b term (constant over n)
// cancels exactly — only x@w_x matters.
#define N_SZ 4096
#define D_SZ 1024

typedef float f32x4 __attribute__((ext_vector_type(4)));

// Kernel 1: partial dot products with ZERO cross-lane operations.
// Rounds 0/1 spent ~24 ds_bpermute (__shfl_down) + lgkmcnt waits per 16 KB
// streamed — a serial tail that capped the stream at ~1.8 TB/s while the
// harness's own fillBuffer proves ~6.4 TB/s at 10% occupancy. Here lane l
// keeps its 16-column partial for each of 4 consecutive rows ("group") and
// stores them as ONE f32x4 to ws[group][lane]: a fully coalesced 1 KB
// wave-store, all 64 lanes active, no LDS, no shuffles, no divergence.
// The 64-way cross-lane sum is deferred to kernel 2 where it is an in-lane
// vector accumulation.
__global__ __launch_bounds__(256) void dot_partial_k(
    const float* __restrict__ x, const float* __restrict__ wx,
    f32x4* __restrict__ ws, int ngroups)
{
    const int lane = threadIdx.x & 63;
    const int wid  = blockIdx.x * (blockDim.x >> 6) + (threadIdx.x >> 6);
    const int nw   = gridDim.x * (blockDim.x >> 6);

    const f32x4* w4 = (const f32x4*)wx;
    const f32x4 w0 = w4[lane];
    const f32x4 w1 = w4[64  + lane];
    const f32x4 w2 = w4[128 + lane];
    const f32x4 w3 = w4[192 + lane];

    // ngroups = 32768; nw = 8192 -> exactly 4 iterations, no tail.
    for (int g = wid; g < ngroups; g += nw) {
        f32x4 a[4][4];
        #pragma unroll
        for (int r = 0; r < 4; ++r) {
            const f32x4* xr = (const f32x4*)(x + (size_t)(4 * g + r) * D_SZ);
            a[r][0] = __builtin_nontemporal_load(xr + lane);
            a[r][1] = __builtin_nontemporal_load(xr + 64  + lane);
            a[r][2] = __builtin_nontemporal_load(xr + 128 + lane);
            a[r][3] = __builtin_nontemporal_load(xr + 192 + lane);
        }

        f32x4 p;
        #pragma unroll
        for (int r = 0; r < 4; ++r) {
            f32x4 acc = a[r][0] * w0;
            acc += a[r][1] * w1;
            acc += a[r][2] * w2;
            acc += a[r][3] * w3;
            p[r] = (acc[0] + acc[1]) + (acc[2] + acc[3]);
        }

        // Regular (cached) store: ws is re-read immediately by softmax_k,
        // 32 MB total -> L2/L3 resident.
        ws[(size_t)g * 64 + lane] = p;
    }
}

// Kernel 2: finish the reduction + softmax. One block (1024 thr) per batch
// row; thread t owns logit group g=t (rows 4t..4t+3 of the row): sums the 64
// per-lane partials componentwise (in-lane vector adds — the cross-lane
// reduction of kernel 1 has become thread-private here), then standard
// max/exp/sum softmax over the 4096 logits.
__global__ __launch_bounds__(1024) void softmax_k(
    const f32x4* __restrict__ ws, float* __restrict__ out)
{
    const int b    = blockIdx.x;
    const int t    = threadIdx.x;        // 0..1023, one 4-logit group each
    const int lane = t & 63;
    const int wv   = t >> 6;             // 16 waves
    __shared__ float sred[16];

    const f32x4* wsg = ws + ((size_t)b * 1024 + t) * 64;
    f32x4 s0 = {0.f, 0.f, 0.f, 0.f}, s1 = s0, s2 = s0, s3 = s0;
    #pragma unroll 4
    for (int l = 0; l < 64; l += 4) {
        s0 += wsg[l];
        s1 += wsg[l + 1];
        s2 += wsg[l + 2];
        s3 += wsg[l + 3];
    }
    f32x4 v = (s0 + s1) + (s2 + s3);     // logits for rows 4t..4t+3

    // row max
    float m = fmaxf(fmaxf(v[0], v[1]), fmaxf(v[2], v[3]));
    #pragma unroll
    for (int off = 32; off > 0; off >>= 1)
        m = fmaxf(m, __shfl_down(m, off, 64));
    if (lane == 0) sred[wv] = m;
    __syncthreads();
    m = sred[0];
    #pragma unroll
    for (int i = 1; i < 16; ++i) m = fmaxf(m, sred[i]);   // LDS broadcast reads
    __syncthreads();                                      // sred reused below

    // exp + row sum
    f32x4 e;
    float s = 0.f;
    #pragma unroll
    for (int c = 0; c < 4; ++c) {
        e[c] = expf(v[c] - m);
        s += e[c];
    }
    #pragma unroll
    for (int off = 32; off > 0; off >>= 1)
        s += __shfl_down(s, off, 64);
    if (lane == 0) sred[wv] = s;
    __syncthreads();
    s = 0.f;
    #pragma unroll
    for (int i = 0; i < 16; ++i) s += sred[i];

    const float inv = 1.0f / s;
    f32x4* out4 = (f32x4*)(out + (size_t)b * N_SZ);
    out4[t] = e * inv;                   // coalesced dwordx4 stores
}

extern "C" void kernel_launch(void* const* d_in, const int* in_sizes, int n_in,
                              void* d_out, int out_size, void* d_ws, size_t ws_size,
                              hipStream_t stream) {
    const float* x  = (const float*)d_in[0];   // fixed_inputs [32,4096,1024]
    const float* wx = (const float*)d_in[2];   // w_x [1024]
    // d_in[1] (hidden), d_in[3] (w_h), d_in[4] (b) cancel under softmax.
    float* out = (float*)d_out;                // [32,4096] fp32

    const int nrows   = out_size;              // 131072 = B*N
    const int ngroups = nrows / 4;             // 32768 4-row groups
    f32x4* ws = (f32x4*)d_ws;                  // needs 32 MiB; ws is ~2 GiB

    dot_partial_k<<<2048, 256, 0, stream>>>(x, wx, ws, ngroups);
    softmax_k<<<nrows / N_SZ, 1024, 0, stream>>>(ws, out);
}

// Round 3
// 673.934 us; speedup vs baseline: 1.0400x; 1.0400x over previous
//
#include <hip/hip_runtime.h>
#include <math.h>

// Problem constants (B, N, D_IN, D_STATE) = (32, 4096, 1024, 1024).
// softmax is shift-invariant, so the hidden@w_h + b term (constant over n)
// cancels exactly — only x@w_x matters.
#define N_SZ 4096
#define D_SZ 1024

typedef float f32x4 __attribute__((ext_vector_type(4)));

// Kernel 1: logits for 4 consecutive rows per wave, ONE group per wave
// (no persistent loop). Round 0-2 postmortem: the stream was pinned at
// ~1.7 TB/s regardless of shuffles/batching => Little's-law says only ~2-3
// loads in flight per wave. Cause: __launch_bounds__(256) (no min-waves)
// makes the backend target a ~64-VGPR budget, so the 64-VGPR 16-load batch
// gets serialized load->wait->use. Fixes here:
//   - __launch_bounds__(256, 2): VGPR cap 256, full batch stays live.
//   - straight-line body (8192 blocks, wave churn like fillBuffer) so the
//     scheduler has no cross-iteration register reuse to respect.
//   - plain (cached) loads: free L3 hits if any of x survives.
__global__ __launch_bounds__(256, 2) void logits_k(
    const float* __restrict__ x, const float* __restrict__ wx,
    float* __restrict__ out)
{
    const int lane = threadIdx.x & 63;
    const int g    = blockIdx.x * 4 + (threadIdx.x >> 6);   // 4-row group id

    const f32x4* w4 = (const f32x4*)wx;
    const f32x4 w0 = w4[lane];
    const f32x4 w1 = w4[64  + lane];
    const f32x4 w2 = w4[128 + lane];
    const f32x4 w3 = w4[192 + lane];

    // Group g covers rows 4g..4g+3 = 16 KB contiguous = 4096 f32x4.
    const f32x4* xg = (const f32x4*)(x + (size_t)g * 4 * D_SZ);

    f32x4 a[4][4];
    #pragma unroll
    for (int r = 0; r < 4; ++r) {
        a[r][0] = xg[r * 256 +       lane];
        a[r][1] = xg[r * 256 + 64  + lane];
        a[r][2] = xg[r * 256 + 128 + lane];
        a[r][3] = xg[r * 256 + 192 + lane];
    }

    float s[4];
    #pragma unroll
    for (int r = 0; r < 4; ++r) {
        f32x4 acc = a[r][0] * w0;
        acc += a[r][1] * w1;
        acc += a[r][2] * w2;
        acc += a[r][3] * w3;
        s[r] = (acc[0] + acc[1]) + (acc[2] + acc[3]);
    }

    // 4 independent butterfly chains; proven ~free (round 2 ablation).
    #pragma unroll
    for (int off = 32; off > 0; off >>= 1) {
        #pragma unroll
        for (int r = 0; r < 4; ++r)
            s[r] += __shfl_down(s[r], off, 64);
    }

    if (lane == 0) {
        f32x4 o = { s[0], s[1], s[2], s[3] };
        *(f32x4*)(out + (size_t)g * 4) = o;   // one dwordx4 store / 16 KB read
    }
}

// Kernel 2: in-place softmax over N=4096 per batch row (round-1 version:
// proven ~15 µs). One block (256 thr) per row; 16 logits/thread in registers.
__global__ __launch_bounds__(256) void softmax_k(float* __restrict__ io)
{
    float* row = io + (size_t)blockIdx.x * N_SZ;
    const int tid  = threadIdx.x;
    const int lane = tid & 63;
    const int wv   = tid >> 6;
    __shared__ float sred[4];

    float v[16];
    float m = -INFINITY;
    #pragma unroll
    for (int j = 0; j < 16; ++j) {
        v[j] = row[tid + j * 256];
        m = fmaxf(m, v[j]);
    }
    #pragma unroll
    for (int off = 32; off > 0; off >>= 1)
        m = fmaxf(m, __shfl_down(m, off, 64));
    if (lane == 0) sred[wv] = m;
    __syncthreads();
    m = fmaxf(fmaxf(sred[0], sred[1]), fmaxf(sred[2], sred[3]));
    __syncthreads();   // sred about to be reused

    float s = 0.0f;
    #pragma unroll
    for (int j = 0; j < 16; ++j) {
        v[j] = expf(v[j] - m);
        s += v[j];
    }
    #pragma unroll
    for (int off = 32; off > 0; off >>= 1)
        s += __shfl_down(s, off, 64);
    if (lane == 0) sred[wv] = s;
    __syncthreads();
    s = sred[0] + sred[1] + sred[2] + sred[3];

    const float inv = 1.0f / s;
    #pragma unroll
    for (int j = 0; j < 16; ++j)
        row[tid + j * 256] = v[j] * inv;
}

extern "C" void kernel_launch(void* const* d_in, const int* in_sizes, int n_in,
                              void* d_out, int out_size, void* d_ws, size_t ws_size,
                              hipStream_t stream) {
    const float* x  = (const float*)d_in[0];   // fixed_inputs [32,4096,1024]
    const float* wx = (const float*)d_in[2];   // w_x [1024]
    // d_in[1] (hidden), d_in[3] (w_h), d_in[4] (b) cancel under softmax.
    float* out = (float*)d_out;                // [32,4096] fp32

    const int nrows = out_size;                // 131072 = B*N
    // One 4-row group per wave: 32768 groups / 4 waves-per-block = 8192 blocks.
    logits_k<<<nrows / 16, 256, 0, stream>>>(x, wx, out);
    softmax_k<<<nrows / N_SZ, 256, 0, stream>>>(out);
}